// Round 12
// baseline (624.254 us; speedup 1.0000x reference)
//
#include <hip/hip_runtime.h>

// ---------------------------------------------------------------------------
// WindowAttention: x[2048,49,512] fp32 -> out[2048,49,512] fp32
// R1: T2 LDS XOR-swizzle + T1 XCD swizzle (bank conflicts -> 0).   [593us]
// R2: 8-phase 256^2 port REGRESSED. R3: raw-barrier RACE. R4: reg-staged
//     fused cvt REGRESSED. R5: counted-vmcnt dbuf NEUTRAL.
// R6: wave-per-head attention.                                     [575us]
// R7: f32-A-staged GEMM1 REGRESSED; token-major qkv KEPT.
// R8: attn no-max softmax + ones-MFMA rowsum; coalesced epilogue.  [573us]
// R9/R10: attn wave-private LDS, no syncthreads, quarter Ps.       [554us]
// R11: GEMM tiles 256x128 w/ 8 waves in the UNCHANGED R1 sync structure:
//      compute-per-barrier 372->930 cyc vs ~400-cyc L2/L3 drain stall
//      (A is L3-resident after cvt-x; FETCH=71MB proves it). acc stays
//      [4][4]/wave -> VGPR ~80; LDS 48KB -> 3 blocks/CU, 24 waves/CU.
// ---------------------------------------------------------------------------

typedef unsigned short ushort_t;
typedef __bf16 bf16x8 __attribute__((ext_vector_type(8)));
typedef float f32x4 __attribute__((ext_vector_type(4)));
typedef unsigned short us8 __attribute__((ext_vector_type(8)));

#define SCALE_F 0.17677669529663687f   // 32^-0.5

// RNE float -> bf16 (as raw ushort)
__device__ __forceinline__ ushort_t f2bf(float f) {
  unsigned u = __builtin_bit_cast(unsigned, f);
  u += 0x7FFFu + ((u >> 16) & 1u);
  return (ushort_t)(u >> 16);
}

// async global->LDS, 16B per lane; lds base must be wave-uniform
__device__ __forceinline__ void gload_lds16(const void* g, void* l) {
  __builtin_amdgcn_global_load_lds(
      (const __attribute__((address_space(1))) void*)g,
      (__attribute__((address_space(3))) void*)l, 16, 0, 0);
}

// wave-local LDS fence: drain ds ops, and stop scheduler hoisting past it
__device__ __forceinline__ void lds_fence() {
  asm volatile("s_waitcnt lgkmcnt(0)" ::: "memory");
  __builtin_amdgcn_sched_barrier(0);
}

// ---------------------------------------------------------------------------
// fp32 -> bf16 conversion, 4 elems/thread
// ---------------------------------------------------------------------------
__global__ __launch_bounds__(256) void k_cvt(const float* __restrict__ in,
                                             ushort_t* __restrict__ out, int n4) {
  int i = blockIdx.x * blockDim.x + threadIdx.x;
  if (i >= n4) return;
  float4 v = reinterpret_cast<const float4*>(in)[i];
  ushort4 o = make_ushort4(f2bf(v.x), f2bf(v.y), f2bf(v.z), f2bf(v.w));
  reinterpret_cast<ushort4*>(out)[i] = o;
}

// ---------------------------------------------------------------------------
// GEMM 256x128 tile, BK=64, 8 waves (512 thr). Wave wv: wm=wv>>1 (M 64-strip),
// wn=wv&1 (N 64-strip); per-wave acc[4][4] of 16x16 frags (identical inner
// loop + swizzle + sync structure to the R1-proven 128^2 kernel).
// A staged rows wv*32..+31 (4 gloads), W rows wv*16..+15 (2 gloads).
// EPI=0: token-major qkv bf16 out. EPI=1: fp32 out.
// ---------------------------------------------------------------------------
template <int EPI>
__global__ __launch_bounds__(512) void k_gemm(const ushort_t* __restrict__ A,
                                              const ushort_t* __restrict__ W,
                                              const float* __restrict__ bias,
                                              ushort_t* __restrict__ out_qkv,
                                              float* __restrict__ out_f,
                                              int nt_o, int ostride) {
  __shared__ __align__(16) ushort_t As[256][64];
  __shared__ __align__(16) ushort_t Ws[128][64];

  const int tid  = threadIdx.x;
  const int lane = tid & 63;
  const int wv   = tid >> 6;          // 0..7
  const int wm   = wv >> 1, wn = wv & 1;

  const int cpx = gridDim.x >> 3;
  const int lid = (blockIdx.x & 7) * cpx + (blockIdx.x >> 3);
  const int bm  = lid / nt_o;
  const int bo  = lid - bm * nt_o;
  const size_t m0 = (size_t)bm * 256;
  const int o0    = bo * 128;

  f32x4 acc[4][4];
#pragma unroll
  for (int i = 0; i < 4; i++)
#pragma unroll
    for (int j = 0; j < 4; j++) acc[i][j] = f32x4{0.f, 0.f, 0.f, 0.f};

  const int subr   = lane >> 3;                       // 0..7
  const int schunk = (((lane & 7) ^ subr) * 8);       // pre-swizzled source col

  for (int kt = 0; kt < 8; ++kt) {
    const int k0 = kt * 64;
    // A: rows wv*32 + i*8 + subr  (i=0..3) -> 256 rows over 8 waves
#pragma unroll
    for (int i = 0; i < 4; i++)
      gload_lds16(A + (m0 + wv * 32 + i * 8 + subr) * 512 + k0 + schunk,
                  &As[wv * 32 + i * 8][0]);
    // W: rows wv*16 + i*8 + subr  (i=0..1) -> 128 rows over 8 waves
#pragma unroll
    for (int i = 0; i < 2; i++)
      gload_lds16(W + (size_t)(o0 + wv * 16 + i * 8 + subr) * 512 + k0 + schunk,
                  &Ws[wv * 16 + i * 8][0]);
    __syncthreads();
    const int fr = lane & 15;
#pragma unroll
    for (int kk = 0; kk < 2; ++kk) {
      const int ch = kk * 4 + (lane >> 4);
      const int cb = ((ch ^ (lane & 7)) << 3);
      uint4 ar[4], br[4];
#pragma unroll
      for (int mi = 0; mi < 4; mi++)
        ar[mi] = *reinterpret_cast<const uint4*>(&As[wm * 64 + mi * 16 + fr][cb]);
#pragma unroll
      for (int ni = 0; ni < 4; ni++)
        br[ni] = *reinterpret_cast<const uint4*>(&Ws[wn * 64 + ni * 16 + fr][cb]);
#pragma unroll
      for (int mi = 0; mi < 4; mi++)
#pragma unroll
        for (int ni = 0; ni < 4; ni++)
          acc[mi][ni] = __builtin_amdgcn_mfma_f32_16x16x32_bf16(
              __builtin_bit_cast(bf16x8, ar[mi]),
              __builtin_bit_cast(bf16x8, br[ni]), acc[mi][ni], 0, 0, 0);
    }
    __syncthreads();
  }

  const int colbase = lane & 15;
  const int rowgrp  = (lane >> 4) * 4;

  if constexpr (EPI == 1) {
#pragma unroll
    for (int ni = 0; ni < 4; ni++) {
      const int o = o0 + wn * 64 + ni * 16 + colbase;
      const float bv = bias[o];
#pragma unroll
      for (int mi = 0; mi < 4; mi++) {
        const size_t mrow = m0 + wm * 64 + mi * 16 + rowgrp;
#pragma unroll
        for (int r = 0; r < 4; r++)
          out_f[(mrow + r) * 512 + o] = acc[mi][ni][r] + bv;
      }
    }
  } else {
#pragma unroll
    for (int mi = 0; mi < 4; mi++) {
#pragma unroll
      for (int r = 0; r < 4; r++) {
        const size_t t = m0 + wm * 64 + mi * 16 + rowgrp + r;
        ushort_t* rowp = out_qkv + t * 1536;
#pragma unroll
        for (int ni = 0; ni < 4; ni++) {
          const int o = o0 + wn * 64 + ni * 16 + colbase;
          rowp[o] = f2bf(acc[mi][ni][r] + bias[o]);
        }
      }
    }
  }
}

// ---------------------------------------------------------------------------
// Attention (R10-proven): wave-per-head, token-major qkv, wave-private LDS,
// no __syncthreads, quarter Ps buffer, no-max softmax + ones-MFMA rowsum.
// ---------------------------------------------------------------------------
__global__ __launch_bounds__(256) void k_attn4(const ushort_t* __restrict__ qkv,
                                               const float* __restrict__ mask,
                                               ushort_t* __restrict__ aout) {
  __shared__ __align__(16) ushort_t Vt[4][32][64];   // per-wave V^T (swizzled)
  __shared__ __align__(16) ushort_t Ps[4][16][64];   // per-wave P quarter-tile

  const int tid  = threadIdx.x;
  const int lane = tid & 63;
  const int wv   = tid >> 6;
  const int blk  = blockIdx.x;
  const int b    = blk >> 2;
  const int h    = (blk & 3) * 4 + wv;
  const int w    = b & 63;
  const size_t tb = (size_t)b * 49 * 1536 + (size_t)h * 32;
  const ushort_t* qb = qkv + tb;          // + n*1536 + d
  const ushort_t* kb = qkv + tb + 512;
  const ushort_t* vb = qkv + tb + 1024;

  {
    uint4* vz = reinterpret_cast<uint4*>(&Vt[wv][0][0]);
#pragma unroll
    for (int i = 0; i < 4; i++) vz[i * 64 + lane] = make_uint4(0, 0, 0, 0);
  }
#pragma unroll
  for (int i = 0; i < 4; i++) {
    const int e = lane + (i << 6);
    if (e < 196) {
      const int n = e >> 2, d0 = (e & 3) * 8;
      uint4 raw = *reinterpret_cast<const uint4*>(vb + (size_t)n * 1536 + d0);
      us8 ev = __builtin_bit_cast(us8, raw);
#pragma unroll
      for (int j = 0; j < 8; j++)
        Vt[wv][d0 + j][(((n >> 3) ^ j) << 3) | (n & 7)] = ev[j];
    }
  }
  lds_fence();   // Vt writes -> vf reads (wave-local)

  const int arow = lane & 15;
  const int kc   = (lane >> 4) * 8;
  const int rg   = (lane >> 4) * 4;

  uint4 vf0[2], vf1[2];
#pragma unroll
  for (int kk = 0; kk < 2; kk++) {
    const int ch = kk * 4 + (lane >> 4);
    const int cb = ((ch ^ (lane & 7)) << 3);
    vf0[kk] = *reinterpret_cast<const uint4*>(&Vt[wv][arow][cb]);
    vf1[kk] = *reinterpret_cast<const uint4*>(&Vt[wv][16 + arow][cb]);
  }

  uint4 kf[4];
#pragma unroll
  for (int ni = 0; ni < 4; ni++)
    kf[ni] = *reinterpret_cast<const uint4*>(kb + (size_t)(ni * 16 + arow) * 1536 + kc);

  bf16x8 ones;
#pragma unroll
  for (int i = 0; i < 8; i++) ones[i] = (__bf16)1.0f;

#pragma unroll
  for (int mt = 0; mt < 4; mt++) {
    {
      uint4 qraw = *reinterpret_cast<const uint4*>(qb + (size_t)(mt * 16 + arow) * 1536 + kc);
      bf16x8 qa = __builtin_bit_cast(bf16x8, qraw);
      f32x4 s[4];
#pragma unroll
      for (int ni = 0; ni < 4; ni++) {
        f32x4 z = {0.f, 0.f, 0.f, 0.f};
        s[ni] = __builtin_amdgcn_mfma_f32_16x16x32_bf16(
            qa, __builtin_bit_cast(bf16x8, kf[ni]), z, 0, 0, 0);
      }
#pragma unroll
      for (int r = 0; r < 4; r++) {
        const int qr = mt * 16 + rg + r;
        const int prow = rg + r;
#pragma unroll
        for (int ni = 0; ni < 4; ni++) {
          const int col = ni * 16 + arow;
          float p;
          if (qr < 49 && col < 49)
            p = __expf(s[ni][r] * SCALE_F + mask[(size_t)w * 2401 + qr * 49 + col]);
          else
            p = 0.f;
          const int pcol = ni * 16 + arow;
          Ps[wv][prow][(((pcol >> 3) ^ (prow & 7)) << 3) | (pcol & 7)] = f2bf(p);
        }
      }
    }
    lds_fence();   // Ps writes -> Ps reads (wave-local RAW)

    {
      f32x4 o0 = {0.f, 0.f, 0.f, 0.f}, o1 = {0.f, 0.f, 0.f, 0.f};
      f32x4 o2 = {0.f, 0.f, 0.f, 0.f};
#pragma unroll
      for (int kk = 0; kk < 2; kk++) {
        const int ch = kk * 4 + (lane >> 4);
        const int cb = ((ch ^ (lane & 7)) << 3);
        uint4 praw = *reinterpret_cast<const uint4*>(&Ps[wv][arow][cb]);
        bf16x8 pa = __builtin_bit_cast(bf16x8, praw);
        o0 = __builtin_amdgcn_mfma_f32_16x16x32_bf16(
            pa, __builtin_bit_cast(bf16x8, vf0[kk]), o0, 0, 0, 0);
        o1 = __builtin_amdgcn_mfma_f32_16x16x32_bf16(
            pa, __builtin_bit_cast(bf16x8, vf1[kk]), o1, 0, 0, 0);
        o2 = __builtin_amdgcn_mfma_f32_16x16x32_bf16(pa, ones, o2, 0, 0, 0);
      }
#pragma unroll
      for (int r = 0; r < 4; r++) {
        const int qr = mt * 16 + rg + r;
        if (qr < 49) {
          const float inv = 1.f / o2[r];
          aout[((size_t)b * 49 + qr) * 512 + h * 32 + arow]      = f2bf(o0[r] * inv);
          aout[((size_t)b * 49 + qr) * 512 + h * 32 + 16 + arow] = f2bf(o1[r] * inv);
        }
      }
    }
  }
}

// ---------------------------------------------------------------------------
// launch
// ---------------------------------------------------------------------------
extern "C" void kernel_launch(void* const* d_in, const int* in_sizes, int n_in,
                              void* d_out, int out_size, void* d_ws, size_t ws_size,
                              hipStream_t stream) {
  const float* x      = (const float*)d_in[0];
  const float* mask   = (const float*)d_in[1];
  const float* W_qkv  = (const float*)d_in[2];
  const float* b_qkv  = (const float*)d_in[3];
  const float* W_proj = (const float*)d_in[4];
  const float* b_proj = (const float*)d_in[5];
  float* out = (float*)d_out;

  // ws layout (bf16 elems): xb | qkv token-major | attn_out | Wqkv_b | Wproj_b
  ushort_t* ws     = (ushort_t*)d_ws;
  ushort_t* xb     = ws;                                  // 51,380,224
  ushort_t* qkvb   = ws + 51380224UL;                     // 154,140,672
  ushort_t* aoutb  = ws + 205520896UL;                    // 51,380,224
  ushort_t* wqkvb  = ws + 256901120UL;                    // 786,432
  ushort_t* wprojb = ws + 257687552UL;                    // 262,144

  const int n4x = 51380224 / 4, n4q = 786432 / 4, n4p = 262144 / 4;
  k_cvt<<<(n4x + 255) / 256, 256, 0, stream>>>(x, xb, n4x);
  k_cvt<<<(n4q + 255) / 256, 256, 0, stream>>>(W_qkv, wqkvb, n4q);
  k_cvt<<<(n4p + 255) / 256, 256, 0, stream>>>(W_proj, wprojb, n4p);

  // GEMM1: [100352,512] x [1536,512]^T -> token-major qkv. 392 x 12 tiles.
  k_gemm<0><<<392 * 12, 512, 0, stream>>>(xb, wqkvb, b_qkv, qkvb, nullptr, 12, 1536);

  // attention: block = 4 heads, wave = 1 head
  k_attn4<<<2048 * 4, 256, 0, stream>>>(qkvb, mask, aoutb);

  // GEMM2: [100352,512] x [512,512]^T + bias -> fp32 out. 392 x 4 tiles.
  k_gemm<1><<<392 * 4, 512, 0, stream>>>(aoutb, wprojb, b_proj, nullptr, out, 4, 512);
}

// Round 13
// 556.852 us; speedup vs baseline: 1.1210x; 1.1210x over previous
//
#include <hip/hip_runtime.h>

// ---------------------------------------------------------------------------
// WindowAttention: x[2048,49,512] fp32 -> out[2048,49,512] fp32
// R1: T2 LDS XOR-swizzle + T1 XCD swizzle (bank conflicts -> 0).   [593us]
// R2/R5/R11: GEMM restructures (8-phase 256^2, counted-vmcnt dbuf, 256x128
//     8-wave) ALL neutral-or-worse at K=512 -> R1-128^2 @260us is the
//     operating point. FROZEN.
// R3: raw-barrier RACE. R4/R7: fused x-cvt variants REGRESSED.
// R6: wave-per-head attention.                                     [575us]
// R8: no-max softmax + ones-MFMA rowsum; token-major qkv.          [573us]
// R9/R10: attn wave-private LDS, no syncthreads, quarter Ps.       [554us]
// R12: attn mask VMEM: pre-transposed maskx[w][qr][arow][ni] float4 loads
//      (64 scalar loads -> 16 coalesced float4, branches gone); SCALE folded
//      into q at GEMM1 epilogue. GEMMs reverted to R10-proven bits.
// ---------------------------------------------------------------------------

typedef unsigned short ushort_t;
typedef __bf16 bf16x8 __attribute__((ext_vector_type(8)));
typedef float f32x4 __attribute__((ext_vector_type(4)));
typedef unsigned short us8 __attribute__((ext_vector_type(8)));

#define SCALE_F 0.17677669529663687f   // 32^-0.5

// RNE float -> bf16 (as raw ushort)
__device__ __forceinline__ ushort_t f2bf(float f) {
  unsigned u = __builtin_bit_cast(unsigned, f);
  u += 0x7FFFu + ((u >> 16) & 1u);
  return (ushort_t)(u >> 16);
}

// async global->LDS, 16B per lane; lds base must be wave-uniform
__device__ __forceinline__ void gload_lds16(const void* g, void* l) {
  __builtin_amdgcn_global_load_lds(
      (const __attribute__((address_space(1))) void*)g,
      (__attribute__((address_space(3))) void*)l, 16, 0, 0);
}

// wave-local LDS fence: drain ds ops, and stop scheduler hoisting past it
__device__ __forceinline__ void lds_fence() {
  asm volatile("s_waitcnt lgkmcnt(0)" ::: "memory");
  __builtin_amdgcn_sched_barrier(0);
}

// ---------------------------------------------------------------------------
// fp32 -> bf16 conversion, 4 elems/thread
// ---------------------------------------------------------------------------
__global__ __launch_bounds__(256) void k_cvt(const float* __restrict__ in,
                                             ushort_t* __restrict__ out, int n4) {
  int i = blockIdx.x * blockDim.x + threadIdx.x;
  if (i >= n4) return;
  float4 v = reinterpret_cast<const float4*>(in)[i];
  ushort4 o = make_ushort4(f2bf(v.x), f2bf(v.y), f2bf(v.z), f2bf(v.w));
  reinterpret_cast<ushort4*>(out)[i] = o;
}

// ---------------------------------------------------------------------------
// mask pre-transpose: maskx[w][qr(64)][arow(16)][ni(4)] f32, pad = -100
// (exp(s-100) flushes to 0 in bf16). 262144 elems.
// ---------------------------------------------------------------------------
__global__ __launch_bounds__(256) void k_maskx(const float* __restrict__ mask,
                                               float* __restrict__ maskx) {
  const int i = blockIdx.x * blockDim.x + threadIdx.x;   // < 262144
  const int ni = i & 3, arow = (i >> 2) & 15, qr = (i >> 6) & 63, w = i >> 12;
  const int col = ni * 16 + arow;
  float v = -100.0f;
  if (qr < 49 && col < 49) v = mask[((size_t)w * 49 + qr) * 49 + col];
  maskx[i] = v;
}

// ---------------------------------------------------------------------------
// GEMM1 (R10-proven): qkv[t][o] = sum_k A[t][k]*W[o][k] + bias[o];
// q region (o<512) additionally scaled by SCALE_F (softmax scale folded in).
// 128x128 tile, BK=64, 4 waves, gload_lds staging, XOR-swizzled LDS.
// Epilogue: token-major [100352][1536] bf16, coalesced.
// ---------------------------------------------------------------------------
__global__ __launch_bounds__(256) void k_gemm1(const ushort_t* __restrict__ A,
                                               const ushort_t* __restrict__ W,
                                               const float* __restrict__ bias,
                                               ushort_t* __restrict__ out_qkv) {
  __shared__ __align__(16) ushort_t As[128][64];
  __shared__ __align__(16) ushort_t Ws[128][64];
  constexpr int nt_o = 12;

  const int tid  = threadIdx.x;
  const int lane = tid & 63;
  const int wv   = tid >> 6;
  const int wr   = wv >> 1, wc = wv & 1;

  const int cpx = gridDim.x >> 3;
  const int lid = (blockIdx.x & 7) * cpx + (blockIdx.x >> 3);
  const int bm  = lid / nt_o;
  const int bo  = lid - bm * nt_o;
  const size_t m0 = (size_t)bm * 128;
  const int o0    = bo * 128;

  f32x4 acc[4][4];
#pragma unroll
  for (int i = 0; i < 4; i++)
#pragma unroll
    for (int j = 0; j < 4; j++) acc[i][j] = f32x4{0.f, 0.f, 0.f, 0.f};

  const int srow   = wv * 32 + (lane >> 3);
  const int schunk = (((lane & 7) ^ (lane >> 3)) * 8);

  for (int kt = 0; kt < 8; ++kt) {
    const int k0 = kt * 64;
#pragma unroll
    for (int i = 0; i < 4; i++)
      gload_lds16(A + (m0 + srow + i * 8) * 512 + k0 + schunk,
                  &As[wv * 32 + i * 8][0]);
#pragma unroll
    for (int i = 0; i < 4; i++)
      gload_lds16(W + (size_t)(o0 + srow + i * 8) * 512 + k0 + schunk,
                  &Ws[wv * 32 + i * 8][0]);
    __syncthreads();
    const int fr = lane & 15;
#pragma unroll
    for (int kk = 0; kk < 2; ++kk) {
      const int ch = kk * 4 + (lane >> 4);
      const int cb = ((ch ^ (lane & 7)) << 3);
      uint4 ar[4], br[4];
#pragma unroll
      for (int mi = 0; mi < 4; mi++)
        ar[mi] = *reinterpret_cast<const uint4*>(&As[wr * 64 + mi * 16 + fr][cb]);
#pragma unroll
      for (int ni = 0; ni < 4; ni++)
        br[ni] = *reinterpret_cast<const uint4*>(&Ws[wc * 64 + ni * 16 + fr][cb]);
#pragma unroll
      for (int mi = 0; mi < 4; mi++)
#pragma unroll
        for (int ni = 0; ni < 4; ni++)
          acc[mi][ni] = __builtin_amdgcn_mfma_f32_16x16x32_bf16(
              __builtin_bit_cast(bf16x8, ar[mi]),
              __builtin_bit_cast(bf16x8, br[ni]), acc[mi][ni], 0, 0, 0);
    }
    __syncthreads();
  }

  const int colbase = lane & 15;
  const int rowgrp  = (lane >> 4) * 4;
#pragma unroll
  for (int mi = 0; mi < 4; mi++) {
#pragma unroll
    for (int r = 0; r < 4; r++) {
      const size_t t = m0 + wr * 64 + mi * 16 + rowgrp + r;
      ushort_t* rowp = out_qkv + t * 1536;
#pragma unroll
      for (int ni = 0; ni < 4; ni++) {
        const int o = o0 + wc * 64 + ni * 16 + colbase;
        float v = acc[mi][ni][r] + bias[o];
        if (o < 512) v *= SCALE_F;            // fold softmax scale into q
        rowp[o] = f2bf(v);
      }
    }
  }
}

// ---------------------------------------------------------------------------
// GEMM2 (R10-proven): out[m][o] = sum_k A[m][k]*W[o][k] + bias[o], fp32 out.
// ---------------------------------------------------------------------------
__global__ __launch_bounds__(256) void k_gemmB(const ushort_t* __restrict__ A,
                                               const ushort_t* __restrict__ W,
                                               const float* __restrict__ bias,
                                               float* __restrict__ out_f,
                                               int nt_o) {
  __shared__ __align__(16) ushort_t As[128][64];
  __shared__ __align__(16) ushort_t Ws[128][64];

  const int tid  = threadIdx.x;
  const int lane = tid & 63;
  const int wv   = tid >> 6;
  const int wr   = wv >> 1, wc = wv & 1;

  const int cpx = gridDim.x >> 3;
  const int lid = (blockIdx.x & 7) * cpx + (blockIdx.x >> 3);
  const int bm  = lid / nt_o;
  const int bo  = lid - bm * nt_o;
  const size_t m0 = (size_t)bm * 128;
  const int o0    = bo * 128;

  f32x4 acc[4][4];
#pragma unroll
  for (int i = 0; i < 4; i++)
#pragma unroll
    for (int j = 0; j < 4; j++) acc[i][j] = f32x4{0.f, 0.f, 0.f, 0.f};

  const int srow   = wv * 32 + (lane >> 3);
  const int schunk = (((lane & 7) ^ (lane >> 3)) * 8);

  for (int kt = 0; kt < 8; ++kt) {
    const int k0 = kt * 64;
#pragma unroll
    for (int i = 0; i < 4; i++)
      gload_lds16(A + (m0 + srow + i * 8) * 512 + k0 + schunk,
                  &As[wv * 32 + i * 8][0]);
#pragma unroll
    for (int i = 0; i < 4; i++)
      gload_lds16(W + (size_t)(o0 + srow + i * 8) * 512 + k0 + schunk,
                  &Ws[wv * 32 + i * 8][0]);
    __syncthreads();
    const int fr = lane & 15;
#pragma unroll
    for (int kk = 0; kk < 2; ++kk) {
      const int ch = kk * 4 + (lane >> 4);
      const int cb = ((ch ^ (lane & 7)) << 3);
      uint4 ar[4], br[4];
#pragma unroll
      for (int mi = 0; mi < 4; mi++)
        ar[mi] = *reinterpret_cast<const uint4*>(&As[wr * 64 + mi * 16 + fr][cb]);
#pragma unroll
      for (int ni = 0; ni < 4; ni++)
        br[ni] = *reinterpret_cast<const uint4*>(&Ws[wc * 64 + ni * 16 + fr][cb]);
#pragma unroll
      for (int mi = 0; mi < 4; mi++)
#pragma unroll
        for (int ni = 0; ni < 4; ni++)
          acc[mi][ni] = __builtin_amdgcn_mfma_f32_16x16x32_bf16(
              __builtin_bit_cast(bf16x8, ar[mi]),
              __builtin_bit_cast(bf16x8, br[ni]), acc[mi][ni], 0, 0, 0);
    }
    __syncthreads();
  }

  const int colbase = lane & 15;
  const int rowgrp  = (lane >> 4) * 4;
#pragma unroll
  for (int ni = 0; ni < 4; ni++) {
    const int o = o0 + wc * 64 + ni * 16 + colbase;
    const float bv = bias[o];
#pragma unroll
    for (int mi = 0; mi < 4; mi++) {
      const size_t mrow = m0 + wr * 64 + mi * 16 + rowgrp;
#pragma unroll
      for (int r = 0; r < 4; r++)
        out_f[(mrow + r) * 512 + o] = acc[mi][ni][r] + bv;
    }
  }
}

// ---------------------------------------------------------------------------
// Attention v6: wave-per-head, token-major qkv, wave-private LDS, no
// __syncthreads, quarter Ps. Mask via pre-transposed maskx float4 loads
// (coalesced, branch-free; pad=-100 -> p=0). q pre-scaled in GEMM1.
// ---------------------------------------------------------------------------
__global__ __launch_bounds__(256) void k_attn4(const ushort_t* __restrict__ qkv,
                                               const float* __restrict__ maskx,
                                               ushort_t* __restrict__ aout) {
  __shared__ __align__(16) ushort_t Vt[4][32][64];   // per-wave V^T (swizzled)
  __shared__ __align__(16) ushort_t Ps[4][16][64];   // per-wave P quarter-tile

  const int tid  = threadIdx.x;
  const int lane = tid & 63;
  const int wv   = tid >> 6;
  const int blk  = blockIdx.x;
  const int b    = blk >> 2;
  const int h    = (blk & 3) * 4 + wv;
  const int w    = b & 63;
  const size_t tb = (size_t)b * 49 * 1536 + (size_t)h * 32;
  const ushort_t* qb = qkv + tb;          // + n*1536 + d
  const ushort_t* kb = qkv + tb + 512;
  const ushort_t* vb = qkv + tb + 1024;

  {
    uint4* vz = reinterpret_cast<uint4*>(&Vt[wv][0][0]);
#pragma unroll
    for (int i = 0; i < 4; i++) vz[i * 64 + lane] = make_uint4(0, 0, 0, 0);
  }
#pragma unroll
  for (int i = 0; i < 4; i++) {
    const int e = lane + (i << 6);
    if (e < 196) {
      const int n = e >> 2, d0 = (e & 3) * 8;
      uint4 raw = *reinterpret_cast<const uint4*>(vb + (size_t)n * 1536 + d0);
      us8 ev = __builtin_bit_cast(us8, raw);
#pragma unroll
      for (int j = 0; j < 8; j++)
        Vt[wv][d0 + j][(((n >> 3) ^ j) << 3) | (n & 7)] = ev[j];
    }
  }
  lds_fence();   // Vt writes -> vf reads (wave-local)

  const int arow = lane & 15;
  const int kc   = (lane >> 4) * 8;
  const int rg   = (lane >> 4) * 4;
  const float* mxb = maskx + ((size_t)w * 64 + rg) * 16 * 4 + (size_t)arow * 4;

  uint4 vf0[2], vf1[2];
#pragma unroll
  for (int kk = 0; kk < 2; kk++) {
    const int ch = kk * 4 + (lane >> 4);
    const int cb = ((ch ^ (lane & 7)) << 3);
    vf0[kk] = *reinterpret_cast<const uint4*>(&Vt[wv][arow][cb]);
    vf1[kk] = *reinterpret_cast<const uint4*>(&Vt[wv][16 + arow][cb]);
  }

  uint4 kf[4];
#pragma unroll
  for (int ni = 0; ni < 4; ni++)
    kf[ni] = *reinterpret_cast<const uint4*>(kb + (size_t)(ni * 16 + arow) * 1536 + kc);

  bf16x8 ones;
#pragma unroll
  for (int i = 0; i < 8; i++) ones[i] = (__bf16)1.0f;

#pragma unroll
  for (int mt = 0; mt < 4; mt++) {
    // ---- S for this mt, exp, store into quarter buffer (branch-free) ----
    {
      uint4 qraw = *reinterpret_cast<const uint4*>(qb + (size_t)(mt * 16 + arow) * 1536 + kc);
      bf16x8 qa = __builtin_bit_cast(bf16x8, qraw);
      f32x4 s[4];
#pragma unroll
      for (int ni = 0; ni < 4; ni++) {
        f32x4 z = {0.f, 0.f, 0.f, 0.f};
        s[ni] = __builtin_amdgcn_mfma_f32_16x16x32_bf16(
            qa, __builtin_bit_cast(bf16x8, kf[ni]), z, 0, 0, 0);
      }
#pragma unroll
      for (int r = 0; r < 4; r++) {
        const int prow = rg + r;
        // one coalesced float4: maskx[w][mt*16+prow][arow][0..4)
        f32x4 mv = *reinterpret_cast<const f32x4*>(mxb + ((size_t)mt * 16 + r) * 64);
#pragma unroll
        for (int ni = 0; ni < 4; ni++) {
          const float p = __expf(s[ni][r] + mv[ni]);   // q pre-scaled; pad->0
          const int pcol = ni * 16 + arow;
          Ps[wv][prow][(((pcol >> 3) ^ (prow & 7)) << 3) | (pcol & 7)] = f2bf(p);
        }
      }
    }
    lds_fence();   // Ps writes -> Ps reads (wave-local RAW)

    // ---- PV for this mt (+ ones-MFMA rowsum) ----
    {
      f32x4 o0 = {0.f, 0.f, 0.f, 0.f}, o1 = {0.f, 0.f, 0.f, 0.f};
      f32x4 o2 = {0.f, 0.f, 0.f, 0.f};
#pragma unroll
      for (int kk = 0; kk < 2; kk++) {
        const int ch = kk * 4 + (lane >> 4);
        const int cb = ((ch ^ (lane & 7)) << 3);
        uint4 praw = *reinterpret_cast<const uint4*>(&Ps[wv][arow][cb]);
        bf16x8 pa = __builtin_bit_cast(bf16x8, praw);
        o0 = __builtin_amdgcn_mfma_f32_16x16x32_bf16(
            pa, __builtin_bit_cast(bf16x8, vf0[kk]), o0, 0, 0, 0);
        o1 = __builtin_amdgcn_mfma_f32_16x16x32_bf16(
            pa, __builtin_bit_cast(bf16x8, vf1[kk]), o1, 0, 0, 0);
        o2 = __builtin_amdgcn_mfma_f32_16x16x32_bf16(pa, ones, o2, 0, 0, 0);
      }
#pragma unroll
      for (int r = 0; r < 4; r++) {
        const int qr = mt * 16 + rg + r;
        if (qr < 49) {
          const float inv = 1.f / o2[r];
          aout[((size_t)b * 49 + qr) * 512 + h * 32 + arow]      = f2bf(o0[r] * inv);
          aout[((size_t)b * 49 + qr) * 512 + h * 32 + 16 + arow] = f2bf(o1[r] * inv);
        }
      }
    }
  }
}

// ---------------------------------------------------------------------------
// launch
// ---------------------------------------------------------------------------
extern "C" void kernel_launch(void* const* d_in, const int* in_sizes, int n_in,
                              void* d_out, int out_size, void* d_ws, size_t ws_size,
                              hipStream_t stream) {
  const float* x      = (const float*)d_in[0];
  const float* mask   = (const float*)d_in[1];
  const float* W_qkv  = (const float*)d_in[2];
  const float* b_qkv  = (const float*)d_in[3];
  const float* W_proj = (const float*)d_in[4];
  const float* b_proj = (const float*)d_in[5];
  float* out = (float*)d_out;

  // ws layout (bf16 elems): xb | qkv token-major | attn_out | Wqkv_b | Wproj_b
  // | maskx (f32, 262144)
  ushort_t* ws     = (ushort_t*)d_ws;
  ushort_t* xb     = ws;                                  // 51,380,224
  ushort_t* qkvb   = ws + 51380224UL;                     // 154,140,672
  ushort_t* aoutb  = ws + 205520896UL;                    // 51,380,224
  ushort_t* wqkvb  = ws + 256901120UL;                    // 786,432
  ushort_t* wprojb = ws + 257687552UL;                    // 262,144
  float*    maskxb = (float*)(ws + 257949696UL);          // 262,144 f32 (1MB)

  const int n4x = 51380224 / 4, n4q = 786432 / 4, n4p = 262144 / 4;
  k_cvt<<<(n4x + 255) / 256, 256, 0, stream>>>(x, xb, n4x);
  k_cvt<<<(n4q + 255) / 256, 256, 0, stream>>>(W_qkv, wqkvb, n4q);
  k_cvt<<<(n4p + 255) / 256, 256, 0, stream>>>(W_proj, wprojb, n4p);
  k_maskx<<<262144 / 256, 256, 0, stream>>>(mask, maskxb);

  // GEMM1: [100352,512] x [1536,512]^T -> token-major qkv (q pre-scaled).
  k_gemm1<<<784 * 12, 256, 0, stream>>>(xb, wqkvb, b_qkv, qkvb);

  // attention: block = 4 heads, wave = 1 head
  k_attn4<<<2048 * 4, 256, 0, stream>>>(qkvb, maskxb, aoutb);

  // GEMM2: [100352,512] x [512,512]^T + bias -> fp32 out.
  k_gemmB<<<784 * 4, 256, 0, stream>>>(aoutb, wprojb, b_proj, out, 4);
}

// Round 14
// 542.036 us; speedup vs baseline: 1.1517x; 1.0273x over previous
//
#include <hip/hip_runtime.h>

// ---------------------------------------------------------------------------
// WindowAttention: x[2048,49,512] fp32 -> out[2048,49,512] fp32
// R1: T2 LDS XOR-swizzle + T1 XCD swizzle (bank conflicts -> 0).   [593us]
// R2/R5/R11: GEMM restructures ALL neutral-or-worse at K=512 -> R1-128^2
//     structure FROZEN. R3: raw-barrier RACE. R4/R7: fused cvt REGRESSED.
// R6: wave-per-head attention.                                     [575us]
// R8: no-max softmax + ones-MFMA rowsum; token-major qkv.          [573us]
// R9/R10: attn wave-private LDS, no syncthreads, quarter Ps.       [554us]
// R12: maskx float4 + scale-in-epilogue -> NEUTRAL, and the o<512 branch
//      cost GEMM1 260->275.
// R13: scale folded into W_qkv/b_qkv at CVT time (epilogue branch-free
//      again); attn lds_fence weakened to compiler-memory-order only
//      (sched_barrier(0) removed -> cross-mt overlap allowed).
// ---------------------------------------------------------------------------

typedef unsigned short ushort_t;
typedef __bf16 bf16x8 __attribute__((ext_vector_type(8)));
typedef float f32x4 __attribute__((ext_vector_type(4)));
typedef unsigned short us8 __attribute__((ext_vector_type(8)));

#define SCALE_F 0.17677669529663687f   // 32^-0.5

// RNE float -> bf16 (as raw ushort)
__device__ __forceinline__ ushort_t f2bf(float f) {
  unsigned u = __builtin_bit_cast(unsigned, f);
  u += 0x7FFFu + ((u >> 16) & 1u);
  return (ushort_t)(u >> 16);
}

// async global->LDS, 16B per lane; lds base must be wave-uniform
__device__ __forceinline__ void gload_lds16(const void* g, void* l) {
  __builtin_amdgcn_global_load_lds(
      (const __attribute__((address_space(1))) void*)g,
      (__attribute__((address_space(3))) void*)l, 16, 0, 0);
}

// wave-local LDS ordering fence: drains DS ops + compiler memory order.
// NO sched_barrier: scheduler may overlap unrelated VALU/VMEM across it
// (DS pipe is in-order per wave; compiler inserts its own waitcnts for
// ds_read->MFMA deps, so the rule-18 hoist case does not apply here).
__device__ __forceinline__ void lds_fence() {
  asm volatile("s_waitcnt lgkmcnt(0)" ::: "memory");
}

// ---------------------------------------------------------------------------
// fp32 -> bf16 conversion, 4 elems/thread
// ---------------------------------------------------------------------------
__global__ __launch_bounds__(256) void k_cvt(const float* __restrict__ in,
                                             ushort_t* __restrict__ out, int n4) {
  int i = blockIdx.x * blockDim.x + threadIdx.x;
  if (i >= n4) return;
  float4 v = reinterpret_cast<const float4*>(in)[i];
  ushort4 o = make_ushort4(f2bf(v.x), f2bf(v.y), f2bf(v.z), f2bf(v.w));
  reinterpret_cast<ushort4*>(out)[i] = o;
}

// W_qkv cvt with q-row pre-scale: rows o<512 (elems < 262144) * SCALE_F.
__global__ __launch_bounds__(256) void k_cvtwq(const float* __restrict__ in,
                                               ushort_t* __restrict__ out, int n4) {
  int i = blockIdx.x * blockDim.x + threadIdx.x;
  if (i >= n4) return;
  const float sc = (i < (262144 / 4)) ? SCALE_F : 1.0f;
  float4 v = reinterpret_cast<const float4*>(in)[i];
  ushort4 o = make_ushort4(f2bf(v.x * sc), f2bf(v.y * sc),
                           f2bf(v.z * sc), f2bf(v.w * sc));
  reinterpret_cast<ushort4*>(out)[i] = o;
}

// scaled qkv bias: bs[i] = b[i] * (i<512 ? SCALE : 1). 1536 elems.
__global__ __launch_bounds__(256) void k_bs(const float* __restrict__ b,
                                            float* __restrict__ bs) {
  int i = blockIdx.x * blockDim.x + threadIdx.x;
  if (i < 1536) bs[i] = b[i] * (i < 512 ? SCALE_F : 1.0f);
}

// ---------------------------------------------------------------------------
// mask pre-transpose: maskx[w][qr(64)][arow(16)][ni(4)] f32, pad = -100.
// ---------------------------------------------------------------------------
__global__ __launch_bounds__(256) void k_maskx(const float* __restrict__ mask,
                                               float* __restrict__ maskx) {
  const int i = blockIdx.x * blockDim.x + threadIdx.x;   // < 262144
  const int ni = i & 3, arow = (i >> 2) & 15, qr = (i >> 6) & 63, w = i >> 12;
  const int col = ni * 16 + arow;
  float v = -100.0f;
  if (qr < 49 && col < 49) v = mask[((size_t)w * 49 + qr) * 49 + col];
  maskx[i] = v;
}

// ---------------------------------------------------------------------------
// GEMM1 (R8-proven bits, branch-free epilogue): qkv[t][o] = sum_k A*W + bs[o]
// (q pre-scaled via W/bias). 128x128 tile, BK=64, 4 waves, gload_lds,
// XOR-swizzled LDS, token-major coalesced epilogue.
// ---------------------------------------------------------------------------
__global__ __launch_bounds__(256) void k_gemm1(const ushort_t* __restrict__ A,
                                               const ushort_t* __restrict__ W,
                                               const float* __restrict__ bias,
                                               ushort_t* __restrict__ out_qkv) {
  __shared__ __align__(16) ushort_t As[128][64];
  __shared__ __align__(16) ushort_t Ws[128][64];
  constexpr int nt_o = 12;

  const int tid  = threadIdx.x;
  const int lane = tid & 63;
  const int wv   = tid >> 6;
  const int wr   = wv >> 1, wc = wv & 1;

  const int cpx = gridDim.x >> 3;
  const int lid = (blockIdx.x & 7) * cpx + (blockIdx.x >> 3);
  const int bm  = lid / nt_o;
  const int bo  = lid - bm * nt_o;
  const size_t m0 = (size_t)bm * 128;
  const int o0    = bo * 128;

  f32x4 acc[4][4];
#pragma unroll
  for (int i = 0; i < 4; i++)
#pragma unroll
    for (int j = 0; j < 4; j++) acc[i][j] = f32x4{0.f, 0.f, 0.f, 0.f};

  const int srow   = wv * 32 + (lane >> 3);
  const int schunk = (((lane & 7) ^ (lane >> 3)) * 8);

  for (int kt = 0; kt < 8; ++kt) {
    const int k0 = kt * 64;
#pragma unroll
    for (int i = 0; i < 4; i++)
      gload_lds16(A + (m0 + srow + i * 8) * 512 + k0 + schunk,
                  &As[wv * 32 + i * 8][0]);
#pragma unroll
    for (int i = 0; i < 4; i++)
      gload_lds16(W + (size_t)(o0 + srow + i * 8) * 512 + k0 + schunk,
                  &Ws[wv * 32 + i * 8][0]);
    __syncthreads();
    const int fr = lane & 15;
#pragma unroll
    for (int kk = 0; kk < 2; ++kk) {
      const int ch = kk * 4 + (lane >> 4);
      const int cb = ((ch ^ (lane & 7)) << 3);
      uint4 ar[4], br[4];
#pragma unroll
      for (int mi = 0; mi < 4; mi++)
        ar[mi] = *reinterpret_cast<const uint4*>(&As[wr * 64 + mi * 16 + fr][cb]);
#pragma unroll
      for (int ni = 0; ni < 4; ni++)
        br[ni] = *reinterpret_cast<const uint4*>(&Ws[wc * 64 + ni * 16 + fr][cb]);
#pragma unroll
      for (int mi = 0; mi < 4; mi++)
#pragma unroll
        for (int ni = 0; ni < 4; ni++)
          acc[mi][ni] = __builtin_amdgcn_mfma_f32_16x16x32_bf16(
              __builtin_bit_cast(bf16x8, ar[mi]),
              __builtin_bit_cast(bf16x8, br[ni]), acc[mi][ni], 0, 0, 0);
    }
    __syncthreads();
  }

  const int colbase = lane & 15;
  const int rowgrp  = (lane >> 4) * 4;
#pragma unroll
  for (int mi = 0; mi < 4; mi++) {
#pragma unroll
    for (int r = 0; r < 4; r++) {
      const size_t t = m0 + wr * 64 + mi * 16 + rowgrp + r;
      ushort_t* rowp = out_qkv + t * 1536;
#pragma unroll
      for (int ni = 0; ni < 4; ni++) {
        const int o = o0 + wc * 64 + ni * 16 + colbase;
        rowp[o] = f2bf(acc[mi][ni][r] + bias[o]);
      }
    }
  }
}

// ---------------------------------------------------------------------------
// GEMM2 (R10-proven): out[m][o] = sum_k A[m][k]*W[o][k] + bias[o], fp32 out.
// ---------------------------------------------------------------------------
__global__ __launch_bounds__(256) void k_gemmB(const ushort_t* __restrict__ A,
                                               const ushort_t* __restrict__ W,
                                               const float* __restrict__ bias,
                                               float* __restrict__ out_f,
                                               int nt_o) {
  __shared__ __align__(16) ushort_t As[128][64];
  __shared__ __align__(16) ushort_t Ws[128][64];

  const int tid  = threadIdx.x;
  const int lane = tid & 63;
  const int wv   = tid >> 6;
  const int wr   = wv >> 1, wc = wv & 1;

  const int cpx = gridDim.x >> 3;
  const int lid = (blockIdx.x & 7) * cpx + (blockIdx.x >> 3);
  const int bm  = lid / nt_o;
  const int bo  = lid - bm * nt_o;
  const size_t m0 = (size_t)bm * 128;
  const int o0    = bo * 128;

  f32x4 acc[4][4];
#pragma unroll
  for (int i = 0; i < 4; i++)
#pragma unroll
    for (int j = 0; j < 4; j++) acc[i][j] = f32x4{0.f, 0.f, 0.f, 0.f};

  const int srow   = wv * 32 + (lane >> 3);
  const int schunk = (((lane & 7) ^ (lane >> 3)) * 8);

  for (int kt = 0; kt < 8; ++kt) {
    const int k0 = kt * 64;
#pragma unroll
    for (int i = 0; i < 4; i++)
      gload_lds16(A + (m0 + srow + i * 8) * 512 + k0 + schunk,
                  &As[wv * 32 + i * 8][0]);
#pragma unroll
    for (int i = 0; i < 4; i++)
      gload_lds16(W + (size_t)(o0 + srow + i * 8) * 512 + k0 + schunk,
                  &Ws[wv * 32 + i * 8][0]);
    __syncthreads();
    const int fr = lane & 15;
#pragma unroll
    for (int kk = 0; kk < 2; ++kk) {
      const int ch = kk * 4 + (lane >> 4);
      const int cb = ((ch ^ (lane & 7)) << 3);
      uint4 ar[4], br[4];
#pragma unroll
      for (int mi = 0; mi < 4; mi++)
        ar[mi] = *reinterpret_cast<const uint4*>(&As[wr * 64 + mi * 16 + fr][cb]);
#pragma unroll
      for (int ni = 0; ni < 4; ni++)
        br[ni] = *reinterpret_cast<const uint4*>(&Ws[wc * 64 + ni * 16 + fr][cb]);
#pragma unroll
      for (int mi = 0; mi < 4; mi++)
#pragma unroll
        for (int ni = 0; ni < 4; ni++)
          acc[mi][ni] = __builtin_amdgcn_mfma_f32_16x16x32_bf16(
              __builtin_bit_cast(bf16x8, ar[mi]),
              __builtin_bit_cast(bf16x8, br[ni]), acc[mi][ni], 0, 0, 0);
    }
    __syncthreads();
  }

  const int colbase = lane & 15;
  const int rowgrp  = (lane >> 4) * 4;
#pragma unroll
  for (int ni = 0; ni < 4; ni++) {
    const int o = o0 + wc * 64 + ni * 16 + colbase;
    const float bv = bias[o];
#pragma unroll
    for (int mi = 0; mi < 4; mi++) {
      const size_t mrow = m0 + wr * 64 + mi * 16 + rowgrp;
#pragma unroll
      for (int r = 0; r < 4; r++)
        out_f[(mrow + r) * 512 + o] = acc[mi][ni][r] + bv;
    }
  }
}

// ---------------------------------------------------------------------------
// Attention v7: wave-per-head, token-major qkv, wave-private LDS, quarter Ps,
// maskx float4, no-max softmax + ones-MFMA rowsum. Fences are memory-order
// only (no sched_barrier) -> scheduler may overlap mt iterations.
// ---------------------------------------------------------------------------
__global__ __launch_bounds__(256) void k_attn4(const ushort_t* __restrict__ qkv,
                                               const float* __restrict__ maskx,
                                               ushort_t* __restrict__ aout) {
  __shared__ __align__(16) ushort_t Vt[4][32][64];   // per-wave V^T (swizzled)
  __shared__ __align__(16) ushort_t Ps[4][16][64];   // per-wave P quarter-tile

  const int tid  = threadIdx.x;
  const int lane = tid & 63;
  const int wv   = tid >> 6;
  const int blk  = blockIdx.x;
  const int b    = blk >> 2;
  const int h    = (blk & 3) * 4 + wv;
  const int w    = b & 63;
  const size_t tb = (size_t)b * 49 * 1536 + (size_t)h * 32;
  const ushort_t* qb = qkv + tb;          // + n*1536 + d
  const ushort_t* kb = qkv + tb + 512;
  const ushort_t* vb = qkv + tb + 1024;

  {
    uint4* vz = reinterpret_cast<uint4*>(&Vt[wv][0][0]);
#pragma unroll
    for (int i = 0; i < 4; i++) vz[i * 64 + lane] = make_uint4(0, 0, 0, 0);
  }
#pragma unroll
  for (int i = 0; i < 4; i++) {
    const int e = lane + (i << 6);
    if (e < 196) {
      const int n = e >> 2, d0 = (e & 3) * 8;
      uint4 raw = *reinterpret_cast<const uint4*>(vb + (size_t)n * 1536 + d0);
      us8 ev = __builtin_bit_cast(us8, raw);
#pragma unroll
      for (int j = 0; j < 8; j++)
        Vt[wv][d0 + j][(((n >> 3) ^ j) << 3) | (n & 7)] = ev[j];
    }
  }
  lds_fence();   // Vt writes -> vf reads (wave-local)

  const int arow = lane & 15;
  const int kc   = (lane >> 4) * 8;
  const int rg   = (lane >> 4) * 4;
  const float* mxb = maskx + ((size_t)w * 64 + rg) * 16 * 4 + (size_t)arow * 4;

  uint4 vf0[2], vf1[2];
#pragma unroll
  for (int kk = 0; kk < 2; kk++) {
    const int ch = kk * 4 + (lane >> 4);
    const int cb = ((ch ^ (lane & 7)) << 3);
    vf0[kk] = *reinterpret_cast<const uint4*>(&Vt[wv][arow][cb]);
    vf1[kk] = *reinterpret_cast<const uint4*>(&Vt[wv][16 + arow][cb]);
  }

  uint4 kf[4];
#pragma unroll
  for (int ni = 0; ni < 4; ni++)
    kf[ni] = *reinterpret_cast<const uint4*>(kb + (size_t)(ni * 16 + arow) * 1536 + kc);

  bf16x8 ones;
#pragma unroll
  for (int i = 0; i < 8; i++) ones[i] = (__bf16)1.0f;

#pragma unroll
  for (int mt = 0; mt < 4; mt++) {
    // ---- S for this mt, exp, store into quarter buffer (branch-free) ----
    {
      uint4 qraw = *reinterpret_cast<const uint4*>(qb + (size_t)(mt * 16 + arow) * 1536 + kc);
      bf16x8 qa = __builtin_bit_cast(bf16x8, qraw);
      f32x4 s[4];
#pragma unroll
      for (int ni = 0; ni < 4; ni++) {
        f32x4 z = {0.f, 0.f, 0.f, 0.f};
        s[ni] = __builtin_amdgcn_mfma_f32_16x16x32_bf16(
            qa, __builtin_bit_cast(bf16x8, kf[ni]), z, 0, 0, 0);
      }
#pragma unroll
      for (int r = 0; r < 4; r++) {
        const int prow = rg + r;
        f32x4 mv = *reinterpret_cast<const f32x4*>(mxb + ((size_t)mt * 16 + r) * 64);
#pragma unroll
        for (int ni = 0; ni < 4; ni++) {
          const float p = __expf(s[ni][r] + mv[ni]);   // q pre-scaled; pad->0
          const int pcol = ni * 16 + arow;
          Ps[wv][prow][(((pcol >> 3) ^ (prow & 7)) << 3) | (pcol & 7)] = f2bf(p);
        }
      }
    }
    lds_fence();   // Ps writes -> Ps reads (wave-local RAW)

    // ---- PV for this mt (+ ones-MFMA rowsum) ----
    {
      f32x4 o0 = {0.f, 0.f, 0.f, 0.f}, o1 = {0.f, 0.f, 0.f, 0.f};
      f32x4 o2 = {0.f, 0.f, 0.f, 0.f};
#pragma unroll
      for (int kk = 0; kk < 2; kk++) {
        const int ch = kk * 4 + (lane >> 4);
        const int cb = ((ch ^ (lane & 7)) << 3);
        uint4 praw = *reinterpret_cast<const uint4*>(&Ps[wv][arow][cb]);
        bf16x8 pa = __builtin_bit_cast(bf16x8, praw);
        o0 = __builtin_amdgcn_mfma_f32_16x16x32_bf16(
            pa, __builtin_bit_cast(bf16x8, vf0[kk]), o0, 0, 0, 0);
        o1 = __builtin_amdgcn_mfma_f32_16x16x32_bf16(
            pa, __builtin_bit_cast(bf16x8, vf1[kk]), o1, 0, 0, 0);
        o2 = __builtin_amdgcn_mfma_f32_16x16x32_bf16(pa, ones, o2, 0, 0, 0);
      }
#pragma unroll
      for (int r = 0; r < 4; r++) {
        const int qr = mt * 16 + rg + r;
        if (qr < 49) {
          const float inv = 1.f / o2[r];
          aout[((size_t)b * 49 + qr) * 512 + h * 32 + arow]      = f2bf(o0[r] * inv);
          aout[((size_t)b * 49 + qr) * 512 + h * 32 + 16 + arow] = f2bf(o1[r] * inv);
        }
      }
    }
    lds_fence();   // Ps reads done -> next-mt writes may land (wave-local WAR)
  }
}

// ---------------------------------------------------------------------------
// launch
// ---------------------------------------------------------------------------
extern "C" void kernel_launch(void* const* d_in, const int* in_sizes, int n_in,
                              void* d_out, int out_size, void* d_ws, size_t ws_size,
                              hipStream_t stream) {
  const float* x      = (const float*)d_in[0];
  const float* mask   = (const float*)d_in[1];
  const float* W_qkv  = (const float*)d_in[2];
  const float* b_qkv  = (const float*)d_in[3];
  const float* W_proj = (const float*)d_in[4];
  const float* b_proj = (const float*)d_in[5];
  float* out = (float*)d_out;

  // ws layout (bf16 elems): xb | qkv token-major | attn_out | Wqkv_b | Wproj_b
  // | maskx (f32 262144) | bscaled (f32 1536)
  ushort_t* ws     = (ushort_t*)d_ws;
  ushort_t* xb     = ws;                                  // 51,380,224
  ushort_t* qkvb   = ws + 51380224UL;                     // 154,140,672
  ushort_t* aoutb  = ws + 205520896UL;                    // 51,380,224
  ushort_t* wqkvb  = ws + 256901120UL;                    // 786,432
  ushort_t* wprojb = ws + 257687552UL;                    // 262,144
  float*    maskxb = (float*)(ws + 257949696UL);          // 262,144 f32
  float*    bscale = (float*)(ws + 258473984UL);          // 1,536 f32

  const int n4x = 51380224 / 4, n4q = 786432 / 4, n4p = 262144 / 4;
  k_cvt<<<(n4x + 255) / 256, 256, 0, stream>>>(x, xb, n4x);
  k_cvtwq<<<(n4q + 255) / 256, 256, 0, stream>>>(W_qkv, wqkvb, n4q);
  k_cvt<<<(n4p + 255) / 256, 256, 0, stream>>>(W_proj, wprojb, n4p);
  k_bs<<<6, 256, 0, stream>>>(b_qkv, bscale);
  k_maskx<<<262144 / 256, 256, 0, stream>>>(mask, maskxb);

  // GEMM1: [100352,512] x [1536,512]^T -> token-major qkv (q pre-scaled).
  k_gemm1<<<784 * 12, 256, 0, stream>>>(xb, wqkvb, bscale, qkvb);

  // attention: block = 4 heads, wave = 1 head
  k_attn4<<<2048 * 4, 256, 0, stream>>>(qkvb, maskxb, aoutb);

  // GEMM2: [100352,512] x [512,512]^T + bias -> fp32 out.
  k_gemmB<<<784 * 4, 256, 0, stream>>>(aoutb, wprojb, b_proj, out, 4);
}